// Round 3
// baseline (460.546 us; speedup 1.0000x reference)
//
#include <hip/hip_runtime.h>
#include <cstdint>
#include <cstddef>

#define NB    2
#define N1    4096
#define N2    16384
#define CF    64
#define KNN   8

// ---------------------------------------------------------------------------
// kernel 0: transpose feat1 [B,C,N1] -> feat1T [B,N1,C]; pack xyz1/flow float4
// ---------------------------------------------------------------------------
__global__ __launch_bounds__(256, 2) void k_pack(
    const float* __restrict__ xyz1, const float* __restrict__ feat1,
    const float* __restrict__ flow,
    float* __restrict__ feat1T, float4* __restrict__ aux4,
    float4* __restrict__ flow4)
{
    __shared__ float tile[64][65];   // [c][n] padded -> conflict-free transpose
    const int b  = blockIdx.y;
    const int n0 = blockIdx.x * 64;
    const int tid = threadIdx.x;
    const int nl = tid & 63, cq = tid >> 6;

#pragma unroll
    for (int r = 0; r < 16; ++r) {
        const int c = r * 4 + cq;
        tile[c][nl] = feat1[((size_t)(b * CF + c)) * N1 + n0 + nl];
    }
    __syncthreads();
#pragma unroll
    for (int r = 0; r < 16; ++r) {
        const int nn = r * 4 + cq;
        feat1T[((size_t)(b * N1 + n0 + nn)) * CF + nl] = tile[nl][nn];
    }
    if (tid < 64) {
        const int n = n0 + tid;
        const float x = xyz1[(b * 3 + 0) * N1 + n];
        const float y = xyz1[(b * 3 + 1) * N1 + n];
        const float z = xyz1[(b * 3 + 2) * N1 + n];
        aux4[b * N1 + n] = make_float4(x, y, z, 0.f);
        const float fx = flow[(b * 3 + 0) * N1 + n];
        const float fy = flow[(b * 3 + 1) * N1 + n];
        const float fz = flow[(b * 3 + 2) * N1 + n];
        flow4[b * N1 + n] = make_float4(fx, fy, fz, 0.f);
    }
}

// ---------------------------------------------------------------------------
// branchless stable top-8 insert. bd ascending; c[s] monotone in s, so every
// position updates independently (flat ~2-op dep chain, no serial bubble-up).
// Strict < keeps the earlier (lower-index) entry on ties, matching top_k.
// ---------------------------------------------------------------------------
__device__ __forceinline__ void topk_insert(float (&bd)[KNN], int (&bi)[KNN],
                                            const float d, const int idx)
{
    const bool c0 = d < bd[0], c1 = d < bd[1], c2 = d < bd[2], c3 = d < bd[3];
    const bool c4 = d < bd[4], c5 = d < bd[5], c6 = d < bd[6], c7 = d < bd[7];
    bd[7] = c6 ? bd[6] : (c7 ? d : bd[7]);  bi[7] = c6 ? bi[6] : (c7 ? idx : bi[7]);
    bd[6] = c5 ? bd[5] : (c6 ? d : bd[6]);  bi[6] = c5 ? bi[5] : (c6 ? idx : bi[6]);
    bd[5] = c4 ? bd[4] : (c5 ? d : bd[5]);  bi[5] = c4 ? bi[4] : (c5 ? idx : bi[5]);
    bd[4] = c3 ? bd[3] : (c4 ? d : bd[4]);  bi[4] = c3 ? bi[3] : (c4 ? idx : bi[4]);
    bd[3] = c2 ? bd[2] : (c3 ? d : bd[3]);  bi[3] = c2 ? bi[2] : (c3 ? idx : bi[3]);
    bd[2] = c1 ? bd[1] : (c2 ? d : bd[2]);  bi[2] = c1 ? bi[1] : (c2 ? idx : bi[2]);
    bd[1] = c0 ? bd[0] : (c1 ? d : bd[1]);  bi[1] = c0 ? bi[0] : (c1 ? idx : bi[1]);
    bd[0] = c0 ? d : bd[0];                 bi[0] = c0 ? idx : bi[0];
}

// ---------------------------------------------------------------------------
// kernel 1: partial KNN. QPT=2 queries/thread, branchless insert.
// launch_bounds(256,2): 2 waves/EU (= grid-limited occupancy) -> 256 VGPR
// budget, kills the scratch spills (R2: VGPR=32, 20.8 GB scratch writes).
// Distance replicates reference fp32 rounding exactly:
// d = (q2 + t2) - (qt + qt), qt = ((qx*tx + qy*ty) + qz*tz), all _rn.
// ---------------------------------------------------------------------------
template <int NS_>
__global__ __launch_bounds__(256, 2) void k_knn2(
    const float* __restrict__ xyz1, const float* __restrict__ xyz2,
    float* __restrict__ partd, int* __restrict__ parti)
{
    constexpr int SPLIT_ = N1 / NS_;
    __shared__ float4 pts[NS_];  // {x, y, z, t2}
    const int sp  = blockIdx.y;
    const int tid = threadIdx.x;
    const int q0  = blockIdx.x * 512 + tid;   // block covers 512 query slots
    const int q1  = q0 + 256;
    const int b   = q0 >> 14;                  // uniform per block (512 | 16384)

    for (int t = tid; t < NS_; t += 256) {
        const int jg = sp * NS_ + t;
        const float x = xyz1[(b * 3 + 0) * N1 + jg];
        const float y = xyz1[(b * 3 + 1) * N1 + jg];
        const float z = xyz1[(b * 3 + 2) * N1 + jg];
        const float t2 = __fadd_rn(__fadd_rn(__fmul_rn(x, x), __fmul_rn(y, y)),
                                   __fmul_rn(z, z));
        pts[t] = make_float4(x, y, z, t2);
    }
    __syncthreads();

    const int n0 = q0 & (N2 - 1), n1 = n0 + 256;
    const float ax = xyz2[(b * 3 + 0) * N2 + n0];
    const float ay = xyz2[(b * 3 + 1) * N2 + n0];
    const float az = xyz2[(b * 3 + 2) * N2 + n0];
    const float a2 = __fadd_rn(__fadd_rn(__fmul_rn(ax, ax), __fmul_rn(ay, ay)),
                               __fmul_rn(az, az));
    const float cx = xyz2[(b * 3 + 0) * N2 + n1];
    const float cy = xyz2[(b * 3 + 1) * N2 + n1];
    const float cz = xyz2[(b * 3 + 2) * N2 + n1];
    const float c2 = __fadd_rn(__fadd_rn(__fmul_rn(cx, cx), __fmul_rn(cy, cy)),
                               __fmul_rn(cz, cz));

    float bdA[KNN], bdB[KNN]; int biA[KNN], biB[KNN];
#pragma unroll
    for (int r = 0; r < KNN; ++r) {
        bdA[r] = INFINITY; biA[r] = 0; bdB[r] = INFINITY; biB[r] = 0;
    }

#pragma unroll 4
    for (int j = 0; j < NS_; ++j) {
        const float4 p = pts[j];
        const int idx = sp * NS_ + j;
        const float qtA = __fadd_rn(
            __fadd_rn(__fmul_rn(ax, p.x), __fmul_rn(ay, p.y)),
            __fmul_rn(az, p.z));
        const float dA = __fsub_rn(__fadd_rn(a2, p.w), __fadd_rn(qtA, qtA));
        const float qtB = __fadd_rn(
            __fadd_rn(__fmul_rn(cx, p.x), __fmul_rn(cy, p.y)),
            __fmul_rn(cz, p.z));
        const float dB = __fsub_rn(__fadd_rn(c2, p.w), __fadd_rn(qtB, qtB));
        topk_insert(bdA, biA, dA, idx);
        topk_insert(bdB, biB, dB, idx);
    }

    {
        float* pd = partd + ((size_t)q0 * SPLIT_ + sp) * KNN;
        int*   pi = parti + ((size_t)q0 * SPLIT_ + sp) * KNN;
#pragma unroll
        for (int r = 0; r < KNN; ++r) { pd[r] = bdA[r]; pi[r] = biA[r]; }
    }
    {
        float* pd = partd + ((size_t)q1 * SPLIT_ + sp) * KNN;
        int*   pi = parti + ((size_t)q1 * SPLIT_ + sp) * KNN;
#pragma unroll
        for (int r = 0; r < KNN; ++r) { pd[r] = bdB[r]; pi[r] = biB[r]; }
    }
}

// ---------------------------------------------------------------------------
// kernel 2: merge partial top-8 lists (ascending split order -> stable ties)
// ---------------------------------------------------------------------------
template <int SPLIT_>
__global__ __launch_bounds__(256, 2) void k_merge2(
    const float* __restrict__ partd, const int* __restrict__ parti,
    int* __restrict__ knn_idx)
{
    const int q = blockIdx.x * 256 + threadIdx.x;
    const float* pd = partd + (size_t)q * SPLIT_ * KNN;
    const int*   pi = parti + (size_t)q * SPLIT_ * KNN;

    float bd[KNN]; int bi[KNN];
#pragma unroll
    for (int r = 0; r < KNN; ++r) { bd[r] = INFINITY; bi[r] = 0; }

#pragma unroll
    for (int t = 0; t < SPLIT_ * KNN; ++t)
        topk_insert(bd, bi, pd[t], pi[t]);

#pragma unroll
    for (int r = 0; r < KNN; ++r) knn_idx[(size_t)q * KNN + r] = bi[r];
}

// ---------------------------------------------------------------------------
// kernel 3: gather + MLP + softmax + weighted flow sum (structure unchanged;
// launch_bounds(256,2) to unlock VGPRs — suspected spilling like k_knn)
// ---------------------------------------------------------------------------
__global__ __launch_bounds__(256, 2) void k_mlp(
    const float* __restrict__ feat1T, const float4* __restrict__ aux4,
    const float4* __restrict__ flow4, const int* __restrict__ knn_idx,
    const float* __restrict__ xyz2,
    const float* __restrict__ W1, const float* __restrict__ b1,
    const float* __restrict__ W2, const float* __restrict__ b2,
    float* __restrict__ out)
{
    constexpr int QPW = 8;   // queries per wave
    __shared__ __align__(16) float w1s[64 * 68];
    __shared__ __align__(16) float inbuf[4][8][68];
    __shared__ __align__(16) float4 flbuf[4][8];

    const int tid = threadIdx.x;
    const int wave = tid >> 6, lane = tid & 63;

    for (int t = tid; t < 64 * 67; t += 256) {
        const int o = t / 67, c = t - o * 67;
        w1s[o * 68 + c] = W1[t];
    }
    if (tid < 64) w1s[tid * 68 + 67] = 0.f;

    const float b1v = b1[lane];
    const float w2a = W2[lane], w2b = W2[64 + lane], w2c = W2[128 + lane];
    const float b20 = b2[0], b21 = b2[1], b22 = b2[2];
    __syncthreads();

    const int k = lane >> 3, p = lane & 7;
    const float* flf = (const float*)&flbuf[wave][0];

    for (int it = 0; it < QPW; ++it) {
        const int q = blockIdx.x * (4 * QPW) + wave * QPW + it;
        const int b = q >> 14, n = q & (N2 - 1);
        __syncthreads();   // protect inbuf/flbuf reuse across iterations

        const int idk = knn_idx[(size_t)q * KNN + k];
        const float4* frow = (const float4*)(feat1T + ((size_t)(b * N1 + idk)) * CF);
        const float4 v0 = frow[p * 2], v1 = frow[p * 2 + 1];
        float4* drow = (float4*)(&inbuf[wave][k][0]);
        drow[p * 2] = v0; drow[p * 2 + 1] = v1;
        if (p == 0) {
            const float4 ax = aux4[b * N1 + idk];
            inbuf[wave][k][64] = ax.x - xyz2[(b * 3 + 0) * N2 + n];
            inbuf[wave][k][65] = ax.y - xyz2[(b * 3 + 1) * N2 + n];
            inbuf[wave][k][66] = ax.z - xyz2[(b * 3 + 2) * N2 + n];
            inbuf[wave][k][67] = 0.f;
        }
        if (p == 1) flbuf[wave][k] = flow4[b * N1 + idk];
        __syncthreads();

        float h[8];
#pragma unroll
        for (int kk = 0; kk < 8; ++kk) h[kk] = b1v;
#pragma unroll
        for (int c4 = 0; c4 < 17; ++c4) {
            const float4 wv = *(const float4*)(&w1s[lane * 68 + c4 * 4]);
#pragma unroll
            for (int kk = 0; kk < 8; ++kk) {
                const float4 iv = *(const float4*)(&inbuf[wave][kk][c4 * 4]);
                h[kk] = fmaf(wv.x, iv.x, h[kk]);
                h[kk] = fmaf(wv.y, iv.y, h[kk]);
                h[kk] = fmaf(wv.z, iv.z, h[kk]);
                h[kk] = fmaf(wv.w, iv.w, h[kk]);
            }
        }

        float s0[8], s1[8], s2[8];
#pragma unroll
        for (int kk = 0; kk < 8; ++kk) {
            float hv = h[kk];
            hv = hv >= 0.f ? hv : 0.1f * hv;
            float p0 = w2a * hv, p1 = w2b * hv, p2 = w2c * hv;
#pragma unroll
            for (int off = 32; off > 0; off >>= 1) {
                p0 += __shfl_xor(p0, off, 64);
                p1 += __shfl_xor(p1, off, 64);
                p2 += __shfl_xor(p2, off, 64);
            }
            s0[kk] = p0 + b20; s1[kk] = p1 + b21; s2[kk] = p2 + b22;
        }

        float res0, res1, res2;
        {
            float m = s0[0];
#pragma unroll
            for (int kk = 1; kk < 8; ++kk) m = fmaxf(m, s0[kk]);
            float S = 0.f, acc = 0.f;
#pragma unroll
            for (int kk = 0; kk < 8; ++kk) {
                const float e = __expf(s0[kk] - m);
                S += e; acc = fmaf(flf[kk * 4 + 0], e, acc);
            }
            res0 = acc / S;
        }
        {
            float m = s1[0];
#pragma unroll
            for (int kk = 1; kk < 8; ++kk) m = fmaxf(m, s1[kk]);
            float S = 0.f, acc = 0.f;
#pragma unroll
            for (int kk = 0; kk < 8; ++kk) {
                const float e = __expf(s1[kk] - m);
                S += e; acc = fmaf(flf[kk * 4 + 1], e, acc);
            }
            res1 = acc / S;
        }
        {
            float m = s2[0];
#pragma unroll
            for (int kk = 1; kk < 8; ++kk) m = fmaxf(m, s2[kk]);
            float S = 0.f, acc = 0.f;
#pragma unroll
            for (int kk = 0; kk < 8; ++kk) {
                const float e = __expf(s2[kk] - m);
                S += e; acc = fmaf(flf[kk * 4 + 2], e, acc);
            }
            res2 = acc / S;
        }

        const float resv = lane == 0 ? res0 : (lane == 1 ? res1 : res2);
        if (lane < 3) out[((size_t)(b * 3 + lane)) * N2 + n] = resv;
    }
}

// ---------------------------------------------------------------------------
extern "C" void kernel_launch(void* const* d_in, const int* in_sizes, int n_in,
                              void* d_out, int out_size, void* d_ws, size_t ws_size,
                              hipStream_t stream)
{
    const float* xyz1  = (const float*)d_in[0];
    const float* xyz2  = (const float*)d_in[1];
    const float* feat1 = (const float*)d_in[2];
    const float* flow  = (const float*)d_in[3];
    const float* W1    = (const float*)d_in[4];
    const float* b1    = (const float*)d_in[5];
    const float* W2    = (const float*)d_in[6];
    const float* b2    = (const float*)d_in[7];
    float* out = (float*)d_out;

    char* ws = (char*)d_ws;
    float*  feat1T  = (float*)(ws);                                   // 2 MiB
    float4* aux4    = (float4*)(ws + (2u << 20));                     // 128 KiB
    float4* flow4   = (float4*)(ws + (2u << 20) + (128u << 10));      // 128 KiB
    int*    knn_idx = (int*)  (ws + (2u << 20) + (256u << 10));       // 1 MiB
    char*   part0   = ws + (3u << 20) + (256u << 10);

    // partd/parti each = SPLIT MiB (32768 q x 8 x 4 B per split)
    const size_t need8 = (size_t)(3u << 20) + (256u << 10) + 2 * 8 * (1u << 20);
    const bool   big   = ws_size >= need8;

    hipLaunchKernelGGL(k_pack, dim3(N1 / 64, NB), dim3(256), 0, stream,
                       xyz1, feat1, flow, feat1T, aux4, flow4);

    if (big) {
        float* partd = (float*)part0;
        int*   parti = (int*)(part0 + (size_t)8 * (1u << 20));
        hipLaunchKernelGGL((k_knn2<512>), dim3(NB * N2 / 512, 8), dim3(256),
                           0, stream, xyz1, xyz2, partd, parti);
        hipLaunchKernelGGL((k_merge2<8>), dim3(NB * N2 / 256), dim3(256),
                           0, stream, partd, parti, knn_idx);
    } else {
        float* partd = (float*)part0;
        int*   parti = (int*)(part0 + (size_t)4 * (1u << 20));
        hipLaunchKernelGGL((k_knn2<1024>), dim3(NB * N2 / 512, 4), dim3(256),
                           0, stream, xyz1, xyz2, partd, parti);
        hipLaunchKernelGGL((k_merge2<4>), dim3(NB * N2 / 256), dim3(256),
                           0, stream, partd, parti, knn_idx);
    }

    hipLaunchKernelGGL(k_mlp, dim3(NB * N2 / 32), dim3(256), 0, stream,
                       feat1T, aux4, flow4, knn_idx, xyz2, W1, b1, W2, b2, out);
}

// Round 4
// 385.710 us; speedup vs baseline: 1.1940x; 1.1940x over previous
//
#include <hip/hip_runtime.h>
#include <cstdint>
#include <cstddef>

#define NB    2
#define N1    4096
#define N2    16384
#define CF    64
#define KNN   8

// ---------------------------------------------------------------------------
// Scalarized stable top-8 state: named scalars only — no local arrays, so the
// state can never land in scratch (R2/R3: array form stayed in scratch memory,
// 20.8 GB of spill writebacks per dispatch regardless of launch_bounds).
// Strict < keeps the earlier (lower-index) entry on ties, matching top_k.
// Descending update order: each line reads pre-update neighbor values.
// ---------------------------------------------------------------------------
#define TKDECL(P) \
    float P##d0=INFINITY,P##d1=INFINITY,P##d2=INFINITY,P##d3=INFINITY, \
          P##d4=INFINITY,P##d5=INFINITY,P##d6=INFINITY,P##d7=INFINITY; \
    int   P##i0=0,P##i1=0,P##i2=0,P##i3=0,P##i4=0,P##i5=0,P##i6=0,P##i7=0

#define TKINS(P, dv, ix) do { \
    const bool c0_ = (dv) < P##d0, c1_ = (dv) < P##d1, c2_ = (dv) < P##d2, c3_ = (dv) < P##d3; \
    const bool c4_ = (dv) < P##d4, c5_ = (dv) < P##d5, c6_ = (dv) < P##d6, c7_ = (dv) < P##d7; \
    P##d7 = c6_ ? P##d6 : (c7_ ? (dv) : P##d7);  P##i7 = c6_ ? P##i6 : (c7_ ? (ix) : P##i7); \
    P##d6 = c5_ ? P##d5 : (c6_ ? (dv) : P##d6);  P##i6 = c5_ ? P##i5 : (c6_ ? (ix) : P##i6); \
    P##d5 = c4_ ? P##d4 : (c5_ ? (dv) : P##d5);  P##i5 = c4_ ? P##i4 : (c5_ ? (ix) : P##i5); \
    P##d4 = c3_ ? P##d3 : (c4_ ? (dv) : P##d4);  P##i4 = c3_ ? P##i3 : (c4_ ? (ix) : P##i4); \
    P##d3 = c2_ ? P##d2 : (c3_ ? (dv) : P##d3);  P##i3 = c2_ ? P##i2 : (c3_ ? (ix) : P##i3); \
    P##d2 = c1_ ? P##d1 : (c2_ ? (dv) : P##d2);  P##i2 = c1_ ? P##i1 : (c2_ ? (ix) : P##i2); \
    P##d1 = c0_ ? P##d0 : (c1_ ? (dv) : P##d1);  P##i1 = c0_ ? P##i0 : (c1_ ? (ix) : P##i1); \
    P##d0 = c0_ ? (dv) : P##d0;                  P##i0 = c0_ ? (ix) : P##i0; \
} while (0)

// ---------------------------------------------------------------------------
// kernel 0: transpose feat1 [B,C,N1] -> feat1T [B,N1,C]; pack xyz1/flow float4
// ---------------------------------------------------------------------------
__global__ __launch_bounds__(256, 2) void k_pack(
    const float* __restrict__ xyz1, const float* __restrict__ feat1,
    const float* __restrict__ flow,
    float* __restrict__ feat1T, float4* __restrict__ aux4,
    float4* __restrict__ flow4)
{
    __shared__ float tile[64][65];
    const int b  = blockIdx.y;
    const int n0 = blockIdx.x * 64;
    const int tid = threadIdx.x;
    const int nl = tid & 63, cq = tid >> 6;

#pragma unroll
    for (int r = 0; r < 16; ++r) {
        const int c = r * 4 + cq;
        tile[c][nl] = feat1[((size_t)(b * CF + c)) * N1 + n0 + nl];
    }
    __syncthreads();
#pragma unroll
    for (int r = 0; r < 16; ++r) {
        const int nn = r * 4 + cq;
        feat1T[((size_t)(b * N1 + n0 + nn)) * CF + nl] = tile[nl][nn];
    }
    if (tid < 64) {
        const int n = n0 + tid;
        const float x = xyz1[(b * 3 + 0) * N1 + n];
        const float y = xyz1[(b * 3 + 1) * N1 + n];
        const float z = xyz1[(b * 3 + 2) * N1 + n];
        aux4[b * N1 + n] = make_float4(x, y, z, 0.f);
        const float fx = flow[(b * 3 + 0) * N1 + n];
        const float fy = flow[(b * 3 + 1) * N1 + n];
        const float fz = flow[(b * 3 + 2) * N1 + n];
        flow4[b * N1 + n] = make_float4(fx, fy, fz, 0.f);
    }
}

// ---------------------------------------------------------------------------
// kernel 1: partial KNN, QPT=2, scalarized top-8 state.
// Distance replicates reference fp32 rounding exactly:
// d = (q2 + t2) - (qt + qt), qt = ((qx*tx + qy*ty) + qz*tz), all _rn.
// ---------------------------------------------------------------------------
template <int NS_>
__global__ __launch_bounds__(256, 2) void k_knn2(
    const float* __restrict__ xyz1, const float* __restrict__ xyz2,
    float* __restrict__ partd, int* __restrict__ parti)
{
    constexpr int SPLIT_ = N1 / NS_;
    __shared__ float4 pts[NS_];  // {x, y, z, t2}
    const int sp  = blockIdx.y;
    const int tid = threadIdx.x;
    const int q0  = blockIdx.x * 512 + tid;
    const int q1  = q0 + 256;
    const int b   = q0 >> 14;    // uniform per block (512 | 16384)

    for (int t = tid; t < NS_; t += 256) {
        const int jg = sp * NS_ + t;
        const float x = xyz1[(b * 3 + 0) * N1 + jg];
        const float y = xyz1[(b * 3 + 1) * N1 + jg];
        const float z = xyz1[(b * 3 + 2) * N1 + jg];
        const float t2 = __fadd_rn(__fadd_rn(__fmul_rn(x, x), __fmul_rn(y, y)),
                                   __fmul_rn(z, z));
        pts[t] = make_float4(x, y, z, t2);
    }
    __syncthreads();

    const int n0 = q0 & (N2 - 1), n1 = n0 + 256;
    const float ax = xyz2[(b * 3 + 0) * N2 + n0];
    const float ay = xyz2[(b * 3 + 1) * N2 + n0];
    const float az = xyz2[(b * 3 + 2) * N2 + n0];
    const float a2 = __fadd_rn(__fadd_rn(__fmul_rn(ax, ax), __fmul_rn(ay, ay)),
                               __fmul_rn(az, az));
    const float cx = xyz2[(b * 3 + 0) * N2 + n1];
    const float cy = xyz2[(b * 3 + 1) * N2 + n1];
    const float cz = xyz2[(b * 3 + 2) * N2 + n1];
    const float c2 = __fadd_rn(__fadd_rn(__fmul_rn(cx, cx), __fmul_rn(cy, cy)),
                               __fmul_rn(cz, cz));

    TKDECL(A);
    TKDECL(B);

#pragma unroll 4
    for (int j = 0; j < NS_; ++j) {
        const float4 p = pts[j];
        const int idx = sp * NS_ + j;
        const float qtA = __fadd_rn(
            __fadd_rn(__fmul_rn(ax, p.x), __fmul_rn(ay, p.y)),
            __fmul_rn(az, p.z));
        const float dA = __fsub_rn(__fadd_rn(a2, p.w), __fadd_rn(qtA, qtA));
        const float qtB = __fadd_rn(
            __fadd_rn(__fmul_rn(cx, p.x), __fmul_rn(cy, p.y)),
            __fmul_rn(cz, p.z));
        const float dB = __fsub_rn(__fadd_rn(c2, p.w), __fadd_rn(qtB, qtB));
        TKINS(A, dA, idx);
        TKINS(B, dB, idx);
    }

    {
        float* pd = partd + ((size_t)q0 * SPLIT_ + sp) * KNN;
        int*   pi = parti + ((size_t)q0 * SPLIT_ + sp) * KNN;
        pd[0]=Ad0; pd[1]=Ad1; pd[2]=Ad2; pd[3]=Ad3; pd[4]=Ad4; pd[5]=Ad5; pd[6]=Ad6; pd[7]=Ad7;
        pi[0]=Ai0; pi[1]=Ai1; pi[2]=Ai2; pi[3]=Ai3; pi[4]=Ai4; pi[5]=Ai5; pi[6]=Ai6; pi[7]=Ai7;
    }
    {
        float* pd = partd + ((size_t)q1 * SPLIT_ + sp) * KNN;
        int*   pi = parti + ((size_t)q1 * SPLIT_ + sp) * KNN;
        pd[0]=Bd0; pd[1]=Bd1; pd[2]=Bd2; pd[3]=Bd3; pd[4]=Bd4; pd[5]=Bd5; pd[6]=Bd6; pd[7]=Bd7;
        pi[0]=Bi0; pi[1]=Bi1; pi[2]=Bi2; pi[3]=Bi3; pi[4]=Bi4; pi[5]=Bi5; pi[6]=Bi6; pi[7]=Bi7;
    }
}

// ---------------------------------------------------------------------------
// kernel 2: merge partial top-8 lists (ascending split order -> stable ties)
// ---------------------------------------------------------------------------
template <int SPLIT_>
__global__ __launch_bounds__(256, 2) void k_merge2(
    const float* __restrict__ partd, const int* __restrict__ parti,
    int* __restrict__ knn_idx)
{
    const int q = blockIdx.x * 256 + threadIdx.x;
    const float* pd = partd + (size_t)q * SPLIT_ * KNN;
    const int*   pi = parti + (size_t)q * SPLIT_ * KNN;

    TKDECL(M);
#pragma unroll
    for (int t = 0; t < SPLIT_ * KNN; ++t) {
        const float d = pd[t];
        const int   i = pi[t];
        TKINS(M, d, i);
    }
    int* ko = knn_idx + (size_t)q * KNN;
    ko[0]=Mi0; ko[1]=Mi1; ko[2]=Mi2; ko[3]=Mi3; ko[4]=Mi4; ko[5]=Mi5; ko[6]=Mi6; ko[7]=Mi7;
}

// ---------------------------------------------------------------------------
// kernel 3: gather + MLP + softmax + weighted flow sum — fully scalarized.
// W1 row held in 17 named float4 registers per lane (loaded once per block
// via LDS); h and logits as named scalars. No local arrays anywhere.
// ---------------------------------------------------------------------------
#define ACC4(h, wv, iv) \
    h = fmaf((wv).x, (iv).x, h); h = fmaf((wv).y, (iv).y, h); \
    h = fmaf((wv).z, (iv).z, h); h = fmaf((wv).w, (iv).w, h)

#define DOT17(h, ivr) do { \
    ACC4(h, w0,  (ivr)[0]);  ACC4(h, w1,  (ivr)[1]);  ACC4(h, w2,  (ivr)[2]); \
    ACC4(h, w3,  (ivr)[3]);  ACC4(h, w4,  (ivr)[4]);  ACC4(h, w5,  (ivr)[5]); \
    ACC4(h, w6,  (ivr)[6]);  ACC4(h, w7,  (ivr)[7]);  ACC4(h, w8,  (ivr)[8]); \
    ACC4(h, w9,  (ivr)[9]);  ACC4(h, w10, (ivr)[10]); ACC4(h, w11, (ivr)[11]); \
    ACC4(h, w12, (ivr)[12]); ACC4(h, w13, (ivr)[13]); ACC4(h, w14, (ivr)[14]); \
    ACC4(h, w15, (ivr)[15]); ACC4(h, w16, (ivr)[16]); \
} while (0)

#define BFLY(p) \
    p += __shfl_xor(p, 32, 64); p += __shfl_xor(p, 16, 64); \
    p += __shfl_xor(p,  8, 64); p += __shfl_xor(p,  4, 64); \
    p += __shfl_xor(p,  2, 64); p += __shfl_xor(p,  1, 64)

#define L2RED(hk, a0, a1, a2) do { \
    float hv_ = (hk); hv_ = hv_ >= 0.f ? hv_ : 0.1f * hv_; \
    float p0_ = w2a * hv_, p1_ = w2b * hv_, p2_ = w2c * hv_; \
    BFLY(p0_); BFLY(p1_); BFLY(p2_); \
    a0 = p0_ + b20; a1 = p1_ + b21; a2 = p2_ + b22; \
} while (0)

#define SMAX8(sa, sb, sc, sd, se, sf, sg, sh, CH, res) do { \
    const float m_ = fmaxf(fmaxf(fmaxf(sa, sb), fmaxf(sc, sd)), \
                           fmaxf(fmaxf(se, sf), fmaxf(sg, sh))); \
    const float e0_ = __expf(sa - m_), e1_ = __expf(sb - m_); \
    const float e2_ = __expf(sc - m_), e3_ = __expf(sd - m_); \
    const float e4_ = __expf(se - m_), e5_ = __expf(sf - m_); \
    const float e6_ = __expf(sg - m_), e7_ = __expf(sh - m_); \
    const float S_ = ((e0_ + e1_) + (e2_ + e3_)) + ((e4_ + e5_) + (e6_ + e7_)); \
    float acc_ = e0_ * flf[0 * 4 + CH]; \
    acc_ = fmaf(e1_, flf[1 * 4 + CH], acc_); acc_ = fmaf(e2_, flf[2 * 4 + CH], acc_); \
    acc_ = fmaf(e3_, flf[3 * 4 + CH], acc_); acc_ = fmaf(e4_, flf[4 * 4 + CH], acc_); \
    acc_ = fmaf(e5_, flf[5 * 4 + CH], acc_); acc_ = fmaf(e6_, flf[6 * 4 + CH], acc_); \
    acc_ = fmaf(e7_, flf[7 * 4 + CH], acc_); \
    res = acc_ / S_; \
} while (0)

__global__ __launch_bounds__(256, 2) void k_mlp(
    const float* __restrict__ feat1T, const float4* __restrict__ aux4,
    const float4* __restrict__ flow4, const int* __restrict__ knn_idx,
    const float* __restrict__ xyz2,
    const float* __restrict__ W1, const float* __restrict__ b1,
    const float* __restrict__ W2, const float* __restrict__ b2,
    float* __restrict__ out)
{
    constexpr int QPW = 8;   // queries per wave
    __shared__ __align__(16) float w1s[64 * 68];
    __shared__ __align__(16) float inbuf[4][8][68];
    __shared__ __align__(16) float4 flbuf[4][8];

    const int tid = threadIdx.x;
    const int wave = tid >> 6, lane = tid & 63;

    for (int t = tid; t < 64 * 67; t += 256) {
        const int o = t / 67, c = t - o * 67;
        w1s[o * 68 + c] = W1[t];
    }
    if (tid < 64) w1s[tid * 68 + 67] = 0.f;

    const float b1v = b1[lane];
    const float w2a = W2[lane], w2b = W2[64 + lane], w2c = W2[128 + lane];
    const float b20 = b2[0], b21 = b2[1], b22 = b2[2];
    __syncthreads();

    // W1 row for this lane -> 17 named float4 registers (one-time LDS read)
    const float4* wr = (const float4*)&w1s[lane * 68];
    const float4 w0 = wr[0],  w1 = wr[1],  w2 = wr[2],  w3 = wr[3];
    const float4 w4 = wr[4],  w5 = wr[5],  w6 = wr[6],  w7 = wr[7];
    const float4 w8 = wr[8],  w9 = wr[9],  w10 = wr[10], w11 = wr[11];
    const float4 w12 = wr[12], w13 = wr[13], w14 = wr[14], w15 = wr[15];
    const float4 w16 = wr[16];

    const int k = lane >> 3, p = lane & 7;
    const float* flf = (const float*)&flbuf[wave][0];

    for (int it = 0; it < QPW; ++it) {
        const int q = blockIdx.x * (4 * QPW) + wave * QPW + it;
        const int b = q >> 14, n = q & (N2 - 1);
        __syncthreads();   // protect inbuf/flbuf reuse across iterations

        const int idk = knn_idx[(size_t)q * KNN + k];
        const float4* frow = (const float4*)(feat1T + ((size_t)(b * N1 + idk)) * CF);
        const float4 g0 = frow[p * 2], g1 = frow[p * 2 + 1];
        float4* drow = (float4*)(&inbuf[wave][k][0]);
        drow[p * 2] = g0; drow[p * 2 + 1] = g1;
        if (p == 0) {
            const float4 axv = aux4[b * N1 + idk];
            inbuf[wave][k][64] = axv.x - xyz2[(b * 3 + 0) * N2 + n];
            inbuf[wave][k][65] = axv.y - xyz2[(b * 3 + 1) * N2 + n];
            inbuf[wave][k][66] = axv.z - xyz2[(b * 3 + 2) * N2 + n];
            inbuf[wave][k][67] = 0.f;
        }
        if (p == 1) flbuf[wave][k] = flow4[b * N1 + idk];
        __syncthreads();

        // layer 1: h_kk = b1[lane] + W1[lane,:] . in[kk,:]
        float h0 = b1v, h1 = b1v, h2 = b1v, h3 = b1v;
        float h4 = b1v, h5 = b1v, h6 = b1v, h7 = b1v;
        DOT17(h0, ((const float4*)&inbuf[wave][0][0]));
        DOT17(h1, ((const float4*)&inbuf[wave][1][0]));
        DOT17(h2, ((const float4*)&inbuf[wave][2][0]));
        DOT17(h3, ((const float4*)&inbuf[wave][3][0]));
        DOT17(h4, ((const float4*)&inbuf[wave][4][0]));
        DOT17(h5, ((const float4*)&inbuf[wave][5][0]));
        DOT17(h6, ((const float4*)&inbuf[wave][6][0]));
        DOT17(h7, ((const float4*)&inbuf[wave][7][0]));

        // leaky relu + layer 2 (3x64 dot via 64-lane butterfly)
        float s00, s01, s02, s03, s04, s05, s06, s07;
        float s10, s11, s12, s13, s14, s15, s16, s17;
        float s20, s21, s22, s23, s24, s25, s26, s27;
        L2RED(h0, s00, s10, s20);
        L2RED(h1, s01, s11, s21);
        L2RED(h2, s02, s12, s22);
        L2RED(h3, s03, s13, s23);
        L2RED(h4, s04, s14, s24);
        L2RED(h5, s05, s15, s25);
        L2RED(h6, s06, s16, s26);
        L2RED(h7, s07, s17, s27);

        float res0, res1, res2;
        SMAX8(s00, s01, s02, s03, s04, s05, s06, s07, 0, res0);
        SMAX8(s10, s11, s12, s13, s14, s15, s16, s17, 1, res1);
        SMAX8(s20, s21, s22, s23, s24, s25, s26, s27, 2, res2);

        const float resv = lane == 0 ? res0 : (lane == 1 ? res1 : res2);
        if (lane < 3) out[((size_t)(b * 3 + lane)) * N2 + n] = resv;
    }
}

// ---------------------------------------------------------------------------
extern "C" void kernel_launch(void* const* d_in, const int* in_sizes, int n_in,
                              void* d_out, int out_size, void* d_ws, size_t ws_size,
                              hipStream_t stream)
{
    const float* xyz1  = (const float*)d_in[0];
    const float* xyz2  = (const float*)d_in[1];
    const float* feat1 = (const float*)d_in[2];
    const float* flow  = (const float*)d_in[3];
    const float* W1    = (const float*)d_in[4];
    const float* b1    = (const float*)d_in[5];
    const float* W2    = (const float*)d_in[6];
    const float* b2    = (const float*)d_in[7];
    float* out = (float*)d_out;

    char* ws = (char*)d_ws;
    float*  feat1T  = (float*)(ws);                                   // 2 MiB
    float4* aux4    = (float4*)(ws + (2u << 20));                     // 128 KiB
    float4* flow4   = (float4*)(ws + (2u << 20) + (128u << 10));      // 128 KiB
    int*    knn_idx = (int*)  (ws + (2u << 20) + (256u << 10));       // 1 MiB
    char*   part0   = ws + (3u << 20) + (256u << 10);

    const size_t need8 = (size_t)(3u << 20) + (256u << 10) + 2 * 8 * (1u << 20);
    const bool   big   = ws_size >= need8;

    hipLaunchKernelGGL(k_pack, dim3(N1 / 64, NB), dim3(256), 0, stream,
                       xyz1, feat1, flow, feat1T, aux4, flow4);

    if (big) {
        float* partd = (float*)part0;
        int*   parti = (int*)(part0 + (size_t)8 * (1u << 20));
        hipLaunchKernelGGL((k_knn2<512>), dim3(NB * N2 / 512, 8), dim3(256),
                           0, stream, xyz1, xyz2, partd, parti);
        hipLaunchKernelGGL((k_merge2<8>), dim3(NB * N2 / 256), dim3(256),
                           0, stream, partd, parti, knn_idx);
    } else {
        float* partd = (float*)part0;
        int*   parti = (int*)(part0 + (size_t)4 * (1u << 20));
        hipLaunchKernelGGL((k_knn2<1024>), dim3(NB * N2 / 512, 4), dim3(256),
                           0, stream, xyz1, xyz2, partd, parti);
        hipLaunchKernelGGL((k_merge2<4>), dim3(NB * N2 / 256), dim3(256),
                           0, stream, partd, parti, knn_idx);
    }

    hipLaunchKernelGGL(k_mlp, dim3(NB * N2 / 32), dim3(256), 0, stream,
                       feat1T, aux4, flow4, knn_idx, xyz2, W1, b1, W2, b2, out);
}